// Round 6
// baseline (890.097 us; speedup 1.0000x reference)
//
#include <hip/hip_runtime.h>
#include <math.h>

#define NN 4096
#define EE 65536
#define H 128
#define NF 4
#define MNODE 8
#define MEDGE 4
#define NT 2

// ---------------- CSR build ----------------
__global__ void k_count(const int* __restrict__ dst, int* __restrict__ cnt) {
  int e = blockIdx.x * 256 + threadIdx.x;
  if (e < EE) atomicAdd(&cnt[dst[e]], 1);
}

__global__ void k_scan(const int* __restrict__ cnt, int* __restrict__ rp) {
  __shared__ int sh[1024];
  int t = threadIdx.x;
  int v0 = cnt[4*t], v1 = cnt[4*t+1], v2 = cnt[4*t+2], v3 = cnt[4*t+3];
  int p1 = v0, p2 = v0 + v1, p3 = p2 + v2, tot = p3 + v3;
  sh[t] = tot; __syncthreads();
  for (int off = 1; off < 1024; off <<= 1) {
    int add = (t >= off) ? sh[t-off] : 0;
    __syncthreads();
    sh[t] += add;
    __syncthreads();
  }
  int base = sh[t] - tot;
  rp[4*t] = base; rp[4*t+1] = base + p1; rp[4*t+2] = base + p2; rp[4*t+3] = base + p3;
  if (t == 1023) rp[NN] = sh[t];
}

__global__ void k_fill(const int* __restrict__ ei, int* __restrict__ cursor, int* __restrict__ cols) {
  int e = blockIdx.x * 256 + threadIdx.x;
  if (e < EE) {
    int d = ei[EE + e], s = ei[e];
    int pos = atomicAdd(&cursor[d], 1);
    cols[pos] = s;
  }
}

__global__ void k_dinv0(const int* __restrict__ cnt, float* __restrict__ d2, float* __restrict__ d1) {
  int i = blockIdx.x * 256 + threadIdx.x;
  if (i < NN) {
    float c = (float)cnt[i];
    d2[i] = 1.f / sqrtf(c + 2.f);
    d1[i] = 1.f / sqrtf(c + 1.f);
  }
}

__global__ void k_pwnorm(const float* __restrict__ pw, float* __restrict__ pwn) {
  int l = blockIdx.x, t = threadIdx.x; // 64 threads
  float a = pw[l*H + t], b = pw[l*H + 64 + t];
  float s = a*a + b*b;
  for (int off = 32; off > 0; off >>= 1) s += __shfl_down(s, off);
  if (t == 0) pwn[l] = sqrtf(s);
}

__global__ void k_segS(const int* __restrict__ dst, const float* __restrict__ me, float* __restrict__ S) {
  int e = blockIdx.x * 256 + threadIdx.x;
  if (e < EE) {
    int d = dst[e];
#pragma unroll
    for (int m = 0; m < MEDGE; m++) atomicAdd(&S[d*MEDGE + m], me[e*MEDGE + m]);
  }
}

// ---------------- device helper: score epilogue (128-thread block) ----------------
__device__ __forceinline__ void score_epilogue(float v, int row, int t,
                                               const float* pw, const float* pwn1,
                                               float* scoreo, unsigned long long* keyso,
                                               int* ranko, float* r2) {
  float sp = v * pw[t];
  for (int off = 32; off > 0; off >>= 1) sp += __shfl_down(sp, off);
  if ((t & 63) == 0) r2[t >> 6] = sp;
  __syncthreads();
  if (t == 0) {
    float s = r2[0] + r2[1];
    float sc = tanhf(s / pwn1[0]);
    scoreo[row] = sc;
    float s2 = sc + 0.0f;
    unsigned u = __float_as_uint(s2);
    u ^= (unsigned)(((int)u >> 31)) | 0x80000000u;
    keyso[row] = ((unsigned long long)u << 12) | (unsigned)(4095 - row);
    ranko[row] = 0;
  }
}

// ---------------- fused edge-MLP input projections ----------------
__global__ void k_mm_cat(const float* __restrict__ F, const float* __restrict__ mn,
                         const float* __restrict__ h, const float* __restrict__ Wm,
                         float* __restrict__ P, float* __restrict__ Q) {
  __shared__ float as[140];
  int row = blockIdx.x, t = threadIdx.x; // 128 threads
  for (int c = t; c < 140; c += 128) {
    float v;
    if (c < NF) v = F[row*NF + c];
    else if (c < NF + MNODE) v = mn[row*MNODE + (c - NF)];
    else v = h[(size_t)row*H + (c - NF - MNODE)];
    as[c] = v;
  }
  __syncthreads();
  const float* BQ = Wm + 140*H;
  float ap = 0.f, aq = 0.f;
  for (int kk = 0; kk < 140; kk++) {
    float a = as[kk];
    ap += a * Wm[kk*H + t];
    aq += a * BQ[kk*H + t];
  }
  P[(size_t)row*H + t] = ap;
  Q[(size_t)row*H + t] = aq;
}

// ---------------- fused: spmm(AQ) + h1 + mm_rb(h1,Wd0)*dinv2 ----------------
__global__ void k_spmm_h1_mm(const float* __restrict__ Q, const int* __restrict__ rp,
                             const int* __restrict__ cols, const float* __restrict__ Pm,
                             const float* __restrict__ bm, const float* __restrict__ S,
                             const float* __restrict__ WmB, const int* __restrict__ cnt,
                             const float* __restrict__ Wd0, const float* __restrict__ dinv2,
                             float* __restrict__ h1, float* __restrict__ tsb) {
  __shared__ float hs[128];
  int i = blockIdx.x, t = threadIdx.x;
  float acc = 0.f;
  int beg = rp[i], end = rp[i+1];
  for (int e = beg; e < end; e++) acc += Q[(size_t)cols[e]*H + t];
  float v = (float)cnt[i] * (Pm[(size_t)i*H + t] + bm[t]) + acc;
#pragma unroll
  for (int m = 0; m < MEDGE; m++) v += S[i*MEDGE + m] * WmB[m*H + t];
  v = fmaxf(v, 0.f);
  h1[(size_t)i*H + t] = v;
  hs[t] = v;
  __syncthreads();
  float a2 = 0.f;
  for (int kk = 0; kk < H; kk++) a2 += hs[kk] * Wd0[kk*H + t];
  tsb[(size_t)i*H + t] = a2 * dinv2[i];
}

// SpMM over CSR rows; if dinv!=null apply GCN epilogue; optional score epilogue
__global__ void k_spmm_fused(const float* __restrict__ ts, const int* __restrict__ rp,
                             const int* __restrict__ cols, const float* __restrict__ dinv,
                             float fill, const float* __restrict__ bias, int relu,
                             float* __restrict__ out,
                             const float* __restrict__ pw, const float* __restrict__ pwn1,
                             float* __restrict__ scoreo, unsigned long long* __restrict__ keyso,
                             int* __restrict__ ranko) {
  __shared__ float r2[2];
  int i = blockIdx.x, t = threadIdx.x;
  float acc = 0.f;
  int beg = rp[i], end = rp[i+1];
  for (int e = beg; e < end; e++) acc += ts[(size_t)cols[e]*H + t];
  float v;
  if (dinv) {
    v = dinv[i] * (acc + fill * ts[(size_t)i*H + t]) + bias[t];
    if (relu) v = fmaxf(v, 0.f);
  } else v = acc;
  out[(size_t)i*H + t] = v;
  if (pw) score_epilogue(v, i, t, pw, pwn1, scoreo, keyso, ranko, r2);
}

// ---------------- top-k pooling (big levels) ----------------
__global__ void k_count_rank(const unsigned long long* __restrict__ keys, int n,
                             int* __restrict__ rank) {
  __shared__ unsigned long long sk[256];
  int t = threadIdx.x;
  int j = blockIdx.y * 256 + t;
  sk[t] = (j < n) ? keys[j] : 0ull;
  __syncthreads();
  int i = blockIdx.x * 256 + t;
  if (i >= n) return;
  unsigned long long ki = keys[i];
  int r = 0;
#pragma unroll 8
  for (int jj = 0; jj < 256; jj++) r += (sk[jj] > ki) ? 1 : 0;
  if (r) atomicAdd(&rank[i], r);
}

__global__ void k_select(const float* __restrict__ score, const int* __restrict__ rank,
                         int n, int k, int* __restrict__ perm, float* __restrict__ sv,
                         int* __restrict__ inv) {
  int i = blockIdx.x * 256 + threadIdx.x;
  if (i < n) {
    int r = rank[i];
    inv[i] = r;
    if (r < k) { perm[r] = i; sv[r] = score[i]; }
  }
}

// pooled matmul: C[row,:] = (x[perm[row],:]*sv[row]) @ B * dinv[row]
__global__ void k_mm_pool(const float* __restrict__ x, const int* __restrict__ perm,
                          const float* __restrict__ sv, const float* __restrict__ B,
                          float* __restrict__ C, const float* __restrict__ dinv) {
  __shared__ float as[128];
  int row = blockIdx.x, t = threadIdx.x;
  as[t] = x[(size_t)perm[row]*H + t] * sv[row];
  __syncthreads();
  float acc = 0.f;
  for (int kk = 0; kk < H; kk++) acc += as[kk] * B[kk*H + t];
  C[(size_t)row*H + t] = acc * dinv[row];
}

// A_820 build with fused rowsum/dinv
__global__ void k_a820_f(const int* __restrict__ rp, const int* __restrict__ cols,
                         const int* __restrict__ perm, float* __restrict__ A820,
                         float* __restrict__ dv) {
  __shared__ float acc[NN];
  __shared__ float red[256];
  int r = blockIdx.x, t = threadIdx.x;
  for (int i = t; i < NN; i += 256) acc[i] = 0.f;
  __syncthreads();
  int pi = perm[r];
  int beg = rp[pi], end = rp[pi+1];
  for (int e = beg + t; e < end; e += 256) { int c = cols[e]; if (c != pi) atomicAdd(&acc[c], 1.f); }
  if (t == 0) atomicAdd(&acc[pi], 1.f);
  for (int e0 = beg; e0 < end; e0++) {
    int c = cols[e0];
    if (c == pi) continue;
    int b2 = rp[c], e2 = rp[c+1];
    for (int e = b2 + t; e < e2; e += 256) { int c2 = cols[e]; if (c2 != c) atomicAdd(&acc[c2], 1.f); }
    if (t == 0) atomicAdd(&acc[c], 1.f);
  }
  __syncthreads();
  float local = 0.f;
  for (int cc = t; cc < 820; cc += 256) {
    float val = (cc == r) ? 0.f : acc[perm[cc]];
    A820[(size_t)r*820 + cc] = val;
    local += val;
  }
  red[t] = local; __syncthreads();
  for (int off = 128; off > 0; off >>= 1) { if (t < off) red[t] += red[t+off]; __syncthreads(); }
  if (t == 0) dv[r] = 1.f / sqrtf(red[0] + 2.f);
}

// column pre-gather (level 1): AP[kk][c] = A[kk][perm[c]]
__global__ void k_gathercols(const float* __restrict__ A, int n, const int* __restrict__ perm,
                             int knext, float* __restrict__ AP) {
  int idx = blockIdx.x * 256 + threadIdx.x;
  int total = n * knext;
  if (idx >= total) return;
  int kk = idx / knext, c = idx - kk * knext;
  AP[idx] = A[(size_t)kk * n + perm[c]];
}

// level-1 augment+pool with fused rowsum/dinv
__global__ void k_augpool2_f(const float* __restrict__ A, const float* __restrict__ AP,
                             int n, const int* __restrict__ perm, int knext,
                             float* __restrict__ out, float* __restrict__ dv) {
  __shared__ float rowb[832];
  __shared__ float red[256];
  int r = blockIdx.x, t = threadIdx.x;
  int pr = perm[r];
  for (int i = t; i < n; i += 256) rowb[i] = A[(size_t)pr*n + i];
  __syncthreads();
  float local = 0.f;
  for (int c = t; c < knext; c += 256) {
    float dot = 0.f;
#pragma unroll 8
    for (int kk = 0; kk < n; kk++) dot += rowb[kk] * AP[(size_t)kk*knext + c];
    float val = (c == r) ? 0.f : (dot + 2.f * AP[(size_t)pr*knext + c]);
    out[(size_t)r*knext + c] = val;
    local += val;
  }
  red[t] = local; __syncthreads();
  for (int off = 128; off > 0; off >>= 1) { if (t < off) red[t] += red[t+off]; __syncthreads(); }
  if (t == 0) dv[r] = 1.f / sqrtf(red[0] + 2.f);
}

// dense GCN apply (branch-free streaming); optional score epilogue
__global__ void k_dense_gcn(const float* __restrict__ A, int n, const float* __restrict__ ts,
                            const float* __restrict__ dinv, float fill, const float* __restrict__ bias,
                            int relu, float* __restrict__ out,
                            const float* __restrict__ pw, const float* __restrict__ pwn1,
                            float* __restrict__ scoreo, unsigned long long* __restrict__ keyso,
                            int* __restrict__ ranko) {
  __shared__ float r2[2];
  int i = blockIdx.x, t = threadIdx.x;
  const float* Ar = A + (size_t)i * n;
  float acc = 0.f;
  int kk = 0;
  int n4 = n & ~3;
#pragma unroll 2
  for (; kk < n4; kk += 4) {
    float a0 = Ar[kk+0], a1 = Ar[kk+1], a2 = Ar[kk+2], a3 = Ar[kk+3];
    float t0 = ts[(size_t)(kk+0)*H + t];
    float t1 = ts[(size_t)(kk+1)*H + t];
    float t2 = ts[(size_t)(kk+2)*H + t];
    float t3 = ts[(size_t)(kk+3)*H + t];
    acc += a0*t0; acc += a1*t1; acc += a2*t2; acc += a3*t3;
  }
  for (; kk < n; kk++) acc += Ar[kk] * ts[(size_t)kk*H + t];
  float v = dinv[i] * (acc + fill * ts[(size_t)i*H + t]) + bias[t];
  if (relu) v = fmaxf(v, 0.f);
  out[(size_t)i*H + t] = v;
  if (pw) score_epilogue(v, i, t, pw, pwn1, scoreo, keyso, ranko, r2);
}

// up-path fused: (residual + inverse-perm scatter of xcur) @ W * dinv
__global__ void k_upproj(const float* __restrict__ xs, const int* __restrict__ inv,
                         const float* __restrict__ xcur, int kk,
                         const float* __restrict__ W, const float* __restrict__ dinv,
                         float* __restrict__ tsb) {
  __shared__ float hs[128];
  int i = blockIdx.x, t = threadIdx.x;
  int r = inv[i];
  float v = xs[(size_t)i*H + t];
  if (r < kk) v += xcur[(size_t)r*H + t];
  hs[t] = v;
  __syncthreads();
  float acc = 0.f;
  for (int k2 = 0; k2 < H; k2++) acc += hs[k2] * W[k2*H + t];
  tsb[(size_t)i*H + t] = acc * dinv[i];
}

// ---------------- deep-levels megakernel ----------------
// down levels 2(164->33), 3(33->7), 4(7->2) + up j=4, j=3. Single workgroup.
__global__ __launch_bounds__(1024) void k_deep(
    const float* __restrict__ x2, const float* __restrict__ A164,
    const unsigned long long* __restrict__ keys2, const float* __restrict__ score2,
    const float* __restrict__ pool_w, const float* __restrict__ pwn,
    const float* __restrict__ Wd, const float* __restrict__ bd,
    const float* __restrict__ Wu, const float* __restrict__ bu,
    int* __restrict__ inv2_g, float* __restrict__ xcur_g) {
  __shared__ float xp_s[33*128];
  __shared__ float tsb_s[33*128];
  __shared__ float x3s[33*128];
  __shared__ float x4s[7*128];
  __shared__ float xc_s[7*128];
  __shared__ float A33s[33*33];
  __shared__ float A7s[49];
  __shared__ float A2s[4];
  __shared__ float dv33s[33], dv7s[7], dv2s[2];
  __shared__ int   perm33[33], perm7[7], perm2[2];
  __shared__ int   inv33[33], inv7[7];
  __shared__ float sv33[33], sv7[7], sv2[2];
  __shared__ unsigned long long ksh[164];
  __shared__ float scs[164];
  const int NTH = 1024;
  int t = threadIdx.x;

  // ===== D2: pool 164 -> 33 =====
  if (t < 164) { ksh[t] = keys2[t]; scs[t] = score2[t]; }
  __syncthreads();
  if (t < 164) {
    unsigned long long ki = ksh[t];
    int r = 0;
    for (int j = 0; j < 164; j++) r += (ksh[j] > ki) ? 1 : 0;
    inv2_g[t] = r;
    if (r < 33) { perm33[r] = t; sv33[r] = scs[t]; }
  }
  __syncthreads();
  for (int o = t; o < 33*128; o += NTH) {
    int r = o >> 7, c = o & 127;
    xp_s[o] = x2[(size_t)perm33[r]*H + c] * sv33[r];
  }
  for (int o = t; o < 33*33; o += NTH) {
    int r = o / 33, c = o - r*33;
    int pr = perm33[r], pc = perm33[c];
    const float* Arw = A164 + (size_t)pr*164;
    float dot = 0.f;
    for (int kk = 0; kk < 164; kk++) dot += Arw[kk] * A164[(size_t)kk*164 + pc];
    A33s[o] = (r == c) ? 0.f : (dot + 2.f * Arw[pc]);
  }
  __syncthreads();
  if (t < 33) {
    float s = 0.f;
    for (int c = 0; c < 33; c++) s += A33s[t*33 + c];
    dv33s[t] = 1.f / sqrtf(s + 2.f);
  }
  __syncthreads();
  // mm L2: tsb = (xp @ Wd2) * dv33
  {
    const float* Wd2 = Wd + 2*H*H;
    if (t < 128) {
      float acc[33];
#pragma unroll
      for (int r = 0; r < 33; r++) acc[r] = 0.f;
      for (int kk = 0; kk < H; kk++) {
        float w = Wd2[kk*H + t];
#pragma unroll
        for (int r = 0; r < 33; r++) acc[r] += xp_s[r*128 + kk] * w;
      }
#pragma unroll
      for (int r = 0; r < 33; r++) tsb_s[r*128 + t] = acc[r] * dv33s[r];
    }
  }
  __syncthreads();
  // gcn L2 -> x3
  {
    const float* bd2 = bd + 2*H;
    if (t < 128) {
      float acc[33];
#pragma unroll
      for (int r = 0; r < 33; r++) acc[r] = 0.f;
      for (int kk = 0; kk < 33; kk++) {
        float tv = tsb_s[kk*128 + t];
#pragma unroll
        for (int r = 0; r < 33; r++) acc[r] += A33s[r*33 + kk] * tv;
      }
#pragma unroll
      for (int r = 0; r < 33; r++) {
        float v = dv33s[r] * (acc[r] + 2.f * tsb_s[r*128 + t]) + bd2[t];
        x3s[r*128 + t] = fmaxf(v, 0.f);
      }
    }
  }
  __syncthreads();
  // score L3 (pool_w+3H, pwn[3]) over 33 rows of x3
  if (t < 33) {
    const float* pw3 = pool_w + 3*H;
    float s = 0.f;
    for (int c = 0; c < H; c++) s += x3s[t*128 + c] * pw3[c];
    float sc = tanhf(s / pwn[3]);
    scs[t] = sc;
    float s2 = sc + 0.0f;
    unsigned u = __float_as_uint(s2);
    u ^= (unsigned)(((int)u >> 31)) | 0x80000000u;
    ksh[t] = ((unsigned long long)u << 12) | (unsigned)(4095 - t);
  }
  __syncthreads();

  // ===== D3: pool 33 -> 7 =====
  if (t < 33) {
    unsigned long long ki = ksh[t];
    int r = 0;
    for (int j = 0; j < 33; j++) r += (ksh[j] > ki) ? 1 : 0;
    inv33[t] = r;
    if (r < 7) { perm7[r] = t; sv7[r] = scs[t]; }
  }
  __syncthreads();
  for (int o = t; o < 7*128; o += NTH) {
    int r = o >> 7, c = o & 127;
    xp_s[o] = x3s[perm7[r]*128 + c] * sv7[r];
  }
  for (int o = t; o < 49; o += NTH) {
    int r = o / 7, c = o - r*7;
    int pr = perm7[r], pc = perm7[c];
    float dot = 0.f;
    for (int kk = 0; kk < 33; kk++) dot += A33s[pr*33 + kk] * A33s[kk*33 + pc];
    A7s[o] = (r == c) ? 0.f : (dot + 2.f * A33s[pr*33 + pc]);
  }
  __syncthreads();
  if (t < 7) {
    float s = 0.f;
    for (int c = 0; c < 7; c++) s += A7s[t*7 + c];
    dv7s[t] = 1.f / sqrtf(s + 2.f);
  }
  __syncthreads();
  {
    const float* Wd3 = Wd + 3*H*H;
    if (t < 128) {
      float acc[7];
#pragma unroll
      for (int r = 0; r < 7; r++) acc[r] = 0.f;
      for (int kk = 0; kk < H; kk++) {
        float w = Wd3[kk*H + t];
#pragma unroll
        for (int r = 0; r < 7; r++) acc[r] += xp_s[r*128 + kk] * w;
      }
#pragma unroll
      for (int r = 0; r < 7; r++) tsb_s[r*128 + t] = acc[r] * dv7s[r];
    }
  }
  __syncthreads();
  {
    const float* bd3 = bd + 3*H;
    if (t < 128) {
      float acc[7];
#pragma unroll
      for (int r = 0; r < 7; r++) acc[r] = 0.f;
      for (int kk = 0; kk < 7; kk++) {
        float tv = tsb_s[kk*128 + t];
#pragma unroll
        for (int r = 0; r < 7; r++) acc[r] += A7s[r*7 + kk] * tv;
      }
#pragma unroll
      for (int r = 0; r < 7; r++) {
        float v = dv7s[r] * (acc[r] + 2.f * tsb_s[r*128 + t]) + bd3[t];
        x4s[r*128 + t] = fmaxf(v, 0.f);
      }
    }
  }
  __syncthreads();
  // score L4 (pool_w+4H, pwn[4]) over 7 rows of x4
  if (t < 7) {
    const float* pw4 = pool_w + 4*H;
    float s = 0.f;
    for (int c = 0; c < H; c++) s += x4s[t*128 + c] * pw4[c];
    float sc = tanhf(s / pwn[4]);
    scs[t] = sc;
    float s2 = sc + 0.0f;
    unsigned u = __float_as_uint(s2);
    u ^= (unsigned)(((int)u >> 31)) | 0x80000000u;
    ksh[t] = ((unsigned long long)u << 12) | (unsigned)(4095 - t);
  }
  __syncthreads();

  // ===== D4: pool 7 -> 2 =====
  if (t < 7) {
    unsigned long long ki = ksh[t];
    int r = 0;
    for (int j = 0; j < 7; j++) r += (ksh[j] > ki) ? 1 : 0;
    inv7[t] = r;
    if (r < 2) { perm2[r] = t; sv2[r] = scs[t]; }
  }
  __syncthreads();
  for (int o = t; o < 2*128; o += NTH) {
    int r = o >> 7, c = o & 127;
    xp_s[o] = x4s[perm2[r]*128 + c] * sv2[r];
  }
  for (int o = t; o < 4; o += NTH) {
    int r = o >> 1, c = o & 1;
    int pr = perm2[r], pc = perm2[c];
    float dot = 0.f;
    for (int kk = 0; kk < 7; kk++) dot += A7s[pr*7 + kk] * A7s[kk*7 + pc];
    A2s[o] = (r == c) ? 0.f : (dot + 2.f * A7s[pr*7 + pc]);
  }
  __syncthreads();
  if (t < 2) dv2s[t] = 1.f / sqrtf(A2s[t*2] + A2s[t*2+1] + 2.f);
  __syncthreads();
  {
    const float* Wd4 = Wd + 4*H*H;
    if (t < 128) {
      float a0 = 0.f, a1 = 0.f;
      for (int kk = 0; kk < H; kk++) {
        float w = Wd4[kk*H + t];
        a0 += xp_s[kk] * w;
        a1 += xp_s[128 + kk] * w;
      }
      tsb_s[t] = a0 * dv2s[0];
      tsb_s[128 + t] = a1 * dv2s[1];
    }
  }
  __syncthreads();
  {
    const float* bd4 = bd + 4*H;
    if (t < 128) {
      float t0 = tsb_s[t], t1 = tsb_s[128 + t];
      float v0 = dv2s[0] * ((A2s[0]*t0 + A2s[1]*t1) + 2.f*t0) + bd4[t];
      float v1 = dv2s[1] * ((A2s[2]*t0 + A2s[3]*t1) + 2.f*t1) + bd4[t];
      xc_s[t] = fmaxf(v0, 0.f);
      xc_s[128 + t] = fmaxf(v1, 0.f);
    }
  }
  __syncthreads();

  // ===== U4: j=4 (n=7, kk=2), Wu0/bu0, relu =====
  for (int o = t; o < 7*128; o += NTH) {
    int r = o >> 7, c = o & 127;
    int rr = inv7[r];
    float v = x4s[o];
    if (rr < 2) v += xc_s[rr*128 + c];
    xp_s[o] = v;
  }
  __syncthreads();
  {
    if (t < 128) {
      float acc[7];
#pragma unroll
      for (int r = 0; r < 7; r++) acc[r] = 0.f;
      for (int kk = 0; kk < H; kk++) {
        float w = Wu[kk*H + t];
#pragma unroll
        for (int r = 0; r < 7; r++) acc[r] += xp_s[r*128 + kk] * w;
      }
#pragma unroll
      for (int r = 0; r < 7; r++) tsb_s[r*128 + t] = acc[r] * dv7s[r];
    }
  }
  __syncthreads();
  {
    if (t < 128) {
      float acc[7];
#pragma unroll
      for (int r = 0; r < 7; r++) acc[r] = 0.f;
      for (int kk = 0; kk < 7; kk++) {
        float tv = tsb_s[kk*128 + t];
#pragma unroll
        for (int r = 0; r < 7; r++) acc[r] += A7s[r*7 + kk] * tv;
      }
#pragma unroll
      for (int r = 0; r < 7; r++) {
        float v = dv7s[r] * (acc[r] + 2.f * tsb_s[r*128 + t]) + bu[t];
        xc_s[r*128 + t] = fmaxf(v, 0.f);
      }
    }
  }
  __syncthreads();

  // ===== U3: j=3 (n=33, kk=7), Wu1/bu1, relu; write xcur to global =====
  for (int o = t; o < 33*128; o += NTH) {
    int r = o >> 7, c = o & 127;
    int rr = inv33[r];
    float v = x3s[o];
    if (rr < 7) v += xc_s[rr*128 + c];
    xp_s[o] = v;
  }
  __syncthreads();
  {
    const float* Wu1 = Wu + 1*H*H;
    if (t < 128) {
      float acc[33];
#pragma unroll
      for (int r = 0; r < 33; r++) acc[r] = 0.f;
      for (int kk = 0; kk < H; kk++) {
        float w = Wu1[kk*H + t];
#pragma unroll
        for (int r = 0; r < 33; r++) acc[r] += xp_s[r*128 + kk] * w;
      }
#pragma unroll
      for (int r = 0; r < 33; r++) tsb_s[r*128 + t] = acc[r] * dv33s[r];
    }
  }
  __syncthreads();
  {
    const float* bu1 = bu + 1*H;
    if (t < 128) {
      float acc[33];
#pragma unroll
      for (int r = 0; r < 33; r++) acc[r] = 0.f;
      for (int kk = 0; kk < 33; kk++) {
        float tv = tsb_s[kk*128 + t];
#pragma unroll
        for (int r = 0; r < 33; r++) acc[r] += A33s[r*33 + kk] * tv;
      }
#pragma unroll
      for (int r = 0; r < 33; r++) {
        float v = dv33s[r] * (acc[r] + 2.f * tsb_s[r*128 + t]) + bu1[t];
        xcur_g[(size_t)r*H + t] = fmaxf(v, 0.f);
      }
    }
  }
}

// ts2[row,0:4] = dinv1_row * (cat([h1, relu(hbuf)]) @ Wout)[row,:]
__global__ void k_outproj_r(const float* __restrict__ h1, const float* __restrict__ hbuf,
                            const float* __restrict__ Wout, const float* __restrict__ dinv1,
                            float* __restrict__ ts2) {
  int row = blockIdx.x, t = threadIdx.x; // 64 threads
  float p0 = 0.f, p1 = 0.f, p2 = 0.f, p3 = 0.f;
#pragma unroll
  for (int half = 0; half < 2; half++) {
    float a = h1[(size_t)row*H + half*64 + t];
    const float* w = Wout + (half*64 + t)*4;
    p0 += a*w[0]; p1 += a*w[1]; p2 += a*w[2]; p3 += a*w[3];
    float b = fmaxf(hbuf[(size_t)row*H + half*64 + t], 0.f);
    const float* w2 = Wout + (128 + half*64 + t)*4;
    p0 += b*w2[0]; p1 += b*w2[1]; p2 += b*w2[2]; p3 += b*w2[3];
  }
  for (int off = 32; off > 0; off >>= 1) {
    p0 += __shfl_down(p0, off); p1 += __shfl_down(p1, off);
    p2 += __shfl_down(p2, off); p3 += __shfl_down(p3, off);
  }
  if (t == 0) {
    float d = dinv1[row];
    ts2[row*4+0] = d*p0; ts2[row*4+1] = d*p1; ts2[row*4+2] = d*p2; ts2[row*4+3] = d*p3;
  }
}

__global__ void k_gcn_out(const float* __restrict__ ts2, const int* __restrict__ rp,
                          const int* __restrict__ cols, const float* __restrict__ dinv1,
                          const float* __restrict__ bout, float* __restrict__ Fcur,
                          float* __restrict__ dout, int tstep) {
  int i = blockIdx.x, t = threadIdx.x; // 64 threads
  int f = t & 3;
  float acc = 0.f;
  int beg = rp[i], end = rp[i+1];
  for (int e = beg + (t >> 2); e < end; e += 16) acc += ts2[cols[e]*4 + f];
  for (int off = 32; off >= 4; off >>= 1) acc += __shfl_down(acc, off);
  if (t < 4) {
    float v = dinv1[i] * (acc + ts2[i*4 + f]) + bout[f];
    Fcur[i*4 + f] = v;
    dout[i*(NT*NF) + tstep*NF + f] = v;
  }
}

extern "C" void kernel_launch(void* const* d_in, const int* in_sizes, int n_in,
                              void* d_out, int out_size, void* d_ws, size_t ws_size,
                              hipStream_t stream) {
  const float* F0        = (const float*)d_in[0];
  const float* mesh_node = (const float*)d_in[1];
  const float* mesh_edge = (const float*)d_in[2];
  const float* Wm        = (const float*)d_in[3];
  const float* bm        = (const float*)d_in[4];
  const float* Wd0       = (const float*)d_in[5];
  const float* bd0       = (const float*)d_in[6];
  const float* Wd        = (const float*)d_in[7];
  const float* bd        = (const float*)d_in[8];
  const float* pool_w    = (const float*)d_in[9];
  const float* Wu        = (const float*)d_in[10];
  const float* bu        = (const float*)d_in[11];
  const float* Wout      = (const float*)d_in[12];
  const float* bout      = (const float*)d_in[13];
  const int*   ei        = (const int*)d_in[14];
  float* out = (float*)d_out;

  char* p = (char*)d_ws;
  auto carve = [&](size_t bytes) -> char* {
    char* r = p;
    p += (bytes + 255) & ~(size_t)255;
    return r;
  };
  int*   cnt    = (int*)carve((size_t)NN*4);
  int*   rp     = (int*)carve((size_t)(NN+1)*4);
  int*   cursor = (int*)carve((size_t)NN*4);
  int*   cols   = (int*)carve((size_t)EE*4);
  int*   permb  = (int*)carve((size_t)5*832*4);
  float* svb    = (float*)carve((size_t)5*832*4);
  float* dinv2  = (float*)carve((size_t)NN*4);
  float* dinv1  = (float*)carve((size_t)NN*4);
  float* pwn    = (float*)carve(8*4);
  float* S      = (float*)carve((size_t)NN*MEDGE*4);
  int*   invb   = (int*)carve((size_t)5*NN*4);
  float* P      = (float*)carve((size_t)NN*H*4);
  float* Q      = (float*)carve((size_t)NN*H*4);
  float* h1     = (float*)carve((size_t)NN*H*4);
  float* hbuf   = (float*)carve((size_t)NN*H*4);
  float* tsb    = (float*)carve((size_t)NN*H*4);
  float* tmp    = (float*)carve((size_t)NN*H*4);   // AP scratch
  float* x0     = (float*)carve((size_t)NN*H*4);
  float* x1     = (float*)carve((size_t)820*H*4);
  float* x2     = (float*)carve((size_t)164*H*4);
  float* xcur   = (float*)carve((size_t)820*H*4);
  float* score  = (float*)carve((size_t)NN*4);
  unsigned long long* keysb = (unsigned long long*)carve((size_t)NN*8);
  int*   rankb  = (int*)carve((size_t)NN*4);
  float* A820   = (float*)carve((size_t)820*820*4);
  float* A164   = (float*)carve((size_t)164*164*4);
  float* dv820  = (float*)carve(820*4);
  float* dv164  = (float*)carve(164*4);
  float* ts2    = (float*)carve((size_t)NN*NF*4);
  float* Fcur   = (float*)carve((size_t)NN*NF*4);

  float* AP = tmp;

  int* perml[5]; float* svl[5]; int* invl[5];
  for (int l = 0; l < 5; l++) {
    perml[l] = permb + l*832; svl[l] = svb + l*832; invl[l] = invb + l*NN;
  }

  // ---- setup (once per launch) ----
  hipMemsetAsync(cnt, 0, (size_t)NN*4, stream);
  hipMemsetAsync(S, 0, (size_t)NN*MEDGE*4, stream);
  hipMemsetAsync(hbuf, 0, (size_t)NN*H*4, stream);
  k_count<<<EE/256, 256, 0, stream>>>(ei + EE, cnt);
  k_scan<<<1, 1024, 0, stream>>>(cnt, rp);
  hipMemcpyAsync(cursor, rp, (size_t)NN*4, hipMemcpyDeviceToDevice, stream);
  k_fill<<<EE/256, 256, 0, stream>>>(ei, cursor, cols);
  k_dinv0<<<NN/256, 256, 0, stream>>>(cnt, dinv2, dinv1);
  k_pwnorm<<<5, 64, 0, stream>>>(pool_w, pwn);
  k_segS<<<EE/256, 256, 0, stream>>>(ei + EE, mesh_edge, S);
  hipMemcpyAsync(Fcur, F0, (size_t)NN*NF*4, hipMemcpyDeviceToDevice, stream);

  for (int step = 0; step < NT; step++) {
    // edge MLP -> h1 -> Wd0 proj; x0 with L0 score epilogue
    k_mm_cat<<<NN, 128, 0, stream>>>(Fcur, mesh_node, hbuf, Wm, P, Q);
    k_spmm_h1_mm<<<NN, 128, 0, stream>>>(Q, rp, cols, P, bm, S, Wm + 280*H, cnt,
                                         Wd0, dinv2, h1, tsb);
    k_spmm_fused<<<NN, 128, 0, stream>>>(tsb, rp, cols, dinv2, 2.f, bd0, 1, x0,
                                         pool_w, pwn, score, keysb, rankb);

    // L0: pool 4096->820
    k_count_rank<<<dim3(16, 16), 256, 0, stream>>>(keysb, NN, rankb);
    k_select<<<16, 256, 0, stream>>>(score, rankb, NN, 820, perml[0], svl[0], invl[0]);
    k_a820_f<<<820, 256, 0, stream>>>(rp, cols, perml[0], A820, dv820);
    k_mm_pool<<<820, 128, 0, stream>>>(x0, perml[0], svl[0], Wd, tsb, dv820);
    k_dense_gcn<<<820, 128, 0, stream>>>(A820, 820, tsb, dv820, 2.f, bd, 1, x1,
                                         pool_w + H, pwn + 1, score, keysb, rankb);

    // L1: pool 820->164
    k_count_rank<<<dim3(4, 4), 256, 0, stream>>>(keysb, 820, rankb);
    k_select<<<4, 256, 0, stream>>>(score, rankb, 820, 164, perml[1], svl[1], invl[1]);
    k_gathercols<<<(820*164 + 255)/256, 256, 0, stream>>>(A820, 820, perml[1], 164, AP);
    k_augpool2_f<<<164, 256, 0, stream>>>(A820, AP, 820, perml[1], 164, A164, dv164);
    k_mm_pool<<<164, 128, 0, stream>>>(x1, perml[1], svl[1], Wd + 1*H*H, tsb, dv164);
    k_dense_gcn<<<164, 128, 0, stream>>>(A164, 164, tsb, dv164, 2.f, bd + 1*H, 1, x2,
                                         pool_w + 2*H, pwn + 2, score, keysb, rankb);

    // deep levels (down 2-4, up j=4,3) fused
    k_deep<<<1, 1024, 0, stream>>>(x2, A164, keysb, score, pool_w, pwn,
                                   Wd, bd, Wu, bu, invl[2], xcur);

    // up j=2,1,0
    k_upproj<<<164, 128, 0, stream>>>(x2, invl[2], xcur, 33, Wu + 2*H*H, dv164, tsb);
    k_dense_gcn<<<164, 128, 0, stream>>>(A164, 164, tsb, dv164, 2.f, bu + 2*H, 1, xcur,
                                         nullptr, nullptr, nullptr, nullptr, nullptr);
    k_upproj<<<820, 128, 0, stream>>>(x1, invl[1], xcur, 164, Wu + 3*H*H, dv820, tsb);
    k_dense_gcn<<<820, 128, 0, stream>>>(A820, 820, tsb, dv820, 2.f, bu + 3*H, 1, xcur,
                                         nullptr, nullptr, nullptr, nullptr, nullptr);
    k_upproj<<<NN, 128, 0, stream>>>(x0, invl[0], xcur, 820, Wu + 4*H*H, dinv2, tsb);
    k_spmm_fused<<<NN, 128, 0, stream>>>(tsb, rp, cols, dinv2, 2.f, bu + 4*H, 0, hbuf,
                                         nullptr, nullptr, nullptr, nullptr, nullptr);

    // output GCN (fill=1)
    k_outproj_r<<<NN, 64, 0, stream>>>(h1, hbuf, Wout, dinv1, ts2);
    k_gcn_out<<<NN, 64, 0, stream>>>(ts2, rp, cols, dinv1, bout, Fcur, out, step);
  }
}

// Round 8
// 756.292 us; speedup vs baseline: 1.1769x; 1.1769x over previous
//
#include <hip/hip_runtime.h>
#include <math.h>

#define NN 4096
#define EE 65536
#define H 128
#define NF 4
#define MNODE 8
#define MEDGE 4
#define NT 2

// ---------------- CSR build ----------------
__global__ void k_count(const int* __restrict__ dst, int* __restrict__ cnt) {
  int e = blockIdx.x * 256 + threadIdx.x;
  if (e < EE) atomicAdd(&cnt[dst[e]], 1);
}

__global__ void k_scan(const int* __restrict__ cnt, int* __restrict__ rp) {
  __shared__ int sh[1024];
  int t = threadIdx.x;
  int v0 = cnt[4*t], v1 = cnt[4*t+1], v2 = cnt[4*t+2], v3 = cnt[4*t+3];
  int p1 = v0, p2 = v0 + v1, p3 = p2 + v2, tot = p3 + v3;
  sh[t] = tot; __syncthreads();
  for (int off = 1; off < 1024; off <<= 1) {
    int add = (t >= off) ? sh[t-off] : 0;
    __syncthreads();
    sh[t] += add;
    __syncthreads();
  }
  int base = sh[t] - tot;
  rp[4*t] = base; rp[4*t+1] = base + p1; rp[4*t+2] = base + p2; rp[4*t+3] = base + p3;
  if (t == 1023) rp[NN] = sh[t];
}

__global__ void k_fill(const int* __restrict__ ei, int* __restrict__ cursor, int* __restrict__ cols) {
  int e = blockIdx.x * 256 + threadIdx.x;
  if (e < EE) {
    int d = ei[EE + e], s = ei[e];
    int pos = atomicAdd(&cursor[d], 1);
    cols[pos] = s;
  }
}

__global__ void k_dinv0(const int* __restrict__ cnt, float* __restrict__ d2, float* __restrict__ d1) {
  int i = blockIdx.x * 256 + threadIdx.x;
  if (i < NN) {
    float c = (float)cnt[i];
    d2[i] = 1.f / sqrtf(c + 2.f);
    d1[i] = 1.f / sqrtf(c + 1.f);
  }
}

__global__ void k_pwnorm(const float* __restrict__ pw, float* __restrict__ pwn) {
  int l = blockIdx.x, t = threadIdx.x; // 64 threads
  float a = pw[l*H + t], b = pw[l*H + 64 + t];
  float s = a*a + b*b;
  for (int off = 32; off > 0; off >>= 1) s += __shfl_down(s, off);
  if (t == 0) pwn[l] = sqrtf(s);
}

__global__ void k_segS(const int* __restrict__ dst, const float* __restrict__ me, float* __restrict__ S) {
  int e = blockIdx.x * 256 + threadIdx.x;
  if (e < EE) {
    int d = dst[e];
#pragma unroll
    for (int m = 0; m < MEDGE; m++) atomicAdd(&S[d*MEDGE + m], me[e*MEDGE + m]);
  }
}

// ---------------- device helper: score epilogue (128-thread block) ----------------
__device__ __forceinline__ void score_epilogue(float v, int row, int t,
                                               const float* pw, const float* pwn1,
                                               float* scoreo, unsigned long long* keyso,
                                               int* ranko, float* r2) {
  float sp = v * pw[t];
  for (int off = 32; off > 0; off >>= 1) sp += __shfl_down(sp, off);
  if ((t & 63) == 0) r2[t >> 6] = sp;
  __syncthreads();
  if (t == 0) {
    float s = r2[0] + r2[1];
    float sc = tanhf(s / pwn1[0]);
    scoreo[row] = sc;
    float s2 = sc + 0.0f;
    unsigned u = __float_as_uint(s2);
    u ^= (unsigned)(((int)u >> 31)) | 0x80000000u;
    keyso[row] = ((unsigned long long)u << 12) | (unsigned)(4095 - row);
    ranko[row] = 0;
  }
}

// ---------------- fused edge-MLP input projections ----------------
__global__ void k_mm_cat(const float* __restrict__ F, const float* __restrict__ mn,
                         const float* __restrict__ h, const float* __restrict__ Wm,
                         float* __restrict__ P, float* __restrict__ Q) {
  __shared__ float as[140];
  int row = blockIdx.x, t = threadIdx.x; // 128 threads
  for (int c = t; c < 140; c += 128) {
    float v;
    if (c < NF) v = F[row*NF + c];
    else if (c < NF + MNODE) v = mn[row*MNODE + (c - NF)];
    else v = h[(size_t)row*H + (c - NF - MNODE)];
    as[c] = v;
  }
  __syncthreads();
  const float* BQ = Wm + 140*H;
  float ap = 0.f, aq = 0.f;
  for (int kk = 0; kk < 140; kk++) {
    float a = as[kk];
    ap += a * Wm[kk*H + t];
    aq += a * BQ[kk*H + t];
  }
  P[(size_t)row*H + t] = ap;
  Q[(size_t)row*H + t] = aq;
}

// ---------------- fused: spmm(AQ) + h1 + mm_rb(h1,Wd0)*dinv2 ----------------
__global__ void k_spmm_h1_mm(const float* __restrict__ Q, const int* __restrict__ rp,
                             const int* __restrict__ cols, const float* __restrict__ Pm,
                             const float* __restrict__ bm, const float* __restrict__ S,
                             const float* __restrict__ WmB, const int* __restrict__ cnt,
                             const float* __restrict__ Wd0, const float* __restrict__ dinv2,
                             float* __restrict__ h1, float* __restrict__ tsb) {
  __shared__ float hs[128];
  int i = blockIdx.x, t = threadIdx.x;
  float acc = 0.f;
  int beg = rp[i], end = rp[i+1];
  for (int e = beg; e < end; e++) acc += Q[(size_t)cols[e]*H + t];
  float v = (float)cnt[i] * (Pm[(size_t)i*H + t] + bm[t]) + acc;
#pragma unroll
  for (int m = 0; m < MEDGE; m++) v += S[i*MEDGE + m] * WmB[m*H + t];
  v = fmaxf(v, 0.f);
  h1[(size_t)i*H + t] = v;
  hs[t] = v;
  __syncthreads();
  float a2 = 0.f;
  for (int kk = 0; kk < H; kk++) a2 += hs[kk] * Wd0[kk*H + t];
  tsb[(size_t)i*H + t] = a2 * dinv2[i];
}

// SpMM over CSR rows; GCN epilogue; optional score epilogue
__global__ void k_spmm_fused(const float* __restrict__ ts, const int* __restrict__ rp,
                             const int* __restrict__ cols, const float* __restrict__ dinv,
                             float fill, const float* __restrict__ bias, int relu,
                             float* __restrict__ out,
                             const float* __restrict__ pw, const float* __restrict__ pwn1,
                             float* __restrict__ scoreo, unsigned long long* __restrict__ keyso,
                             int* __restrict__ ranko) {
  __shared__ float r2[2];
  int i = blockIdx.x, t = threadIdx.x;
  float acc = 0.f;
  int beg = rp[i], end = rp[i+1];
  for (int e = beg; e < end; e++) acc += ts[(size_t)cols[e]*H + t];
  float v;
  if (dinv) {
    v = dinv[i] * (acc + fill * ts[(size_t)i*H + t]) + bias[t];
    if (relu) v = fmaxf(v, 0.f);
  } else v = acc;
  out[(size_t)i*H + t] = v;
  if (pw) score_epilogue(v, i, t, pw, pwn1, scoreo, keyso, ranko, r2);
}

// ---------------- top-k pooling (big levels) ----------------
__global__ void k_count_rank(const unsigned long long* __restrict__ keys, int n,
                             int* __restrict__ rank) {
  __shared__ unsigned long long sk[256];
  int t = threadIdx.x;
  int j = blockIdx.y * 256 + t;
  sk[t] = (j < n) ? keys[j] : 0ull;
  __syncthreads();
  int i = blockIdx.x * 256 + t;
  if (i >= n) return;
  unsigned long long ki = keys[i];
  int r = 0;
#pragma unroll 8
  for (int jj = 0; jj < 256; jj++) r += (sk[jj] > ki) ? 1 : 0;
  if (r) atomicAdd(&rank[i], r);
}

__global__ void k_select(const float* __restrict__ score, const int* __restrict__ rank,
                         int n, int k, int* __restrict__ perm, float* __restrict__ sv,
                         int* __restrict__ inv) {
  int i = blockIdx.x * 256 + threadIdx.x;
  if (i < n) {
    int r = rank[i];
    inv[i] = r;
    if (r < k) { perm[r] = i; sv[r] = score[i]; }
  }
}

// pooled matmul: C[row,:] = (x[perm[row],:]*sv[row]) @ B * dinv[row]
__global__ void k_mm_pool(const float* __restrict__ x, const int* __restrict__ perm,
                          const float* __restrict__ sv, const float* __restrict__ B,
                          float* __restrict__ C, const float* __restrict__ dinv) {
  __shared__ float as[128];
  int row = blockIdx.x, t = threadIdx.x;
  as[t] = x[(size_t)perm[row]*H + t] * sv[row];
  __syncthreads();
  float acc = 0.f;
  for (int kk = 0; kk < H; kk++) acc += as[kk] * B[kk*H + t];
  C[(size_t)row*H + t] = acc * dinv[row];
}

// generic row-block matmul (K=H)
__global__ void k_mm_rb(const float* __restrict__ A, const float* __restrict__ B,
                        float* __restrict__ C, const float* __restrict__ dinv) {
  __shared__ float as[128];
  int row = blockIdx.x, t = threadIdx.x;
  as[t] = A[(size_t)row*H + t];
  __syncthreads();
  float acc = 0.f;
  for (int kk = 0; kk < H; kk++) acc += as[kk] * B[kk*H + t];
  C[(size_t)row*H + t] = acc * dinv[row];
}

// single-block fused rank+select+poolx for n <= 256
__global__ void k_pool_small(const float* __restrict__ score, const unsigned long long* __restrict__ keys,
                             const float* __restrict__ x, int n, int k,
                             int* __restrict__ perm, float* __restrict__ sv,
                             int* __restrict__ inv, float* __restrict__ xp) {
  __shared__ unsigned long long ks[256];
  __shared__ int permS[40];
  __shared__ float svS[40];
  int t = threadIdx.x; // 256 threads
  ks[t] = (t < n) ? keys[t] : 0ull;
  __syncthreads();
  if (t < n) {
    unsigned long long ki = ks[t];
    int r = 0;
    for (int j = 0; j < n; j++) r += (ks[j] > ki) ? 1 : 0;
    inv[t] = r;
    if (r < k) {
      float sc = score[t];
      permS[r] = t; svS[r] = sc;
      perm[r] = t; sv[r] = sc;
    }
  }
  __syncthreads();
  for (int idx = t; idx < k*H; idx += 256) {
    int r = idx >> 7, c = idx & 127;
    xp[idx] = x[(size_t)permS[r]*H + c] * svS[r];
  }
}

// A_820 build with fused rowsum/dinv
__global__ void k_a820_f(const int* __restrict__ rp, const int* __restrict__ cols,
                         const int* __restrict__ perm, float* __restrict__ A820,
                         float* __restrict__ dv) {
  __shared__ float acc[NN];
  __shared__ float red[256];
  int r = blockIdx.x, t = threadIdx.x;
  for (int i = t; i < NN; i += 256) acc[i] = 0.f;
  __syncthreads();
  int pi = perm[r];
  int beg = rp[pi], end = rp[pi+1];
  for (int e = beg + t; e < end; e += 256) { int c = cols[e]; if (c != pi) atomicAdd(&acc[c], 1.f); }
  if (t == 0) atomicAdd(&acc[pi], 1.f);
  for (int e0 = beg; e0 < end; e0++) {
    int c = cols[e0];
    if (c == pi) continue;
    int b2 = rp[c], e2 = rp[c+1];
    for (int e = b2 + t; e < e2; e += 256) { int c2 = cols[e]; if (c2 != c) atomicAdd(&acc[c2], 1.f); }
    if (t == 0) atomicAdd(&acc[c], 1.f);
  }
  __syncthreads();
  float local = 0.f;
  for (int cc = t; cc < 820; cc += 256) {
    float val = (cc == r) ? 0.f : acc[perm[cc]];
    A820[(size_t)r*820 + cc] = val;
    local += val;
  }
  red[t] = local; __syncthreads();
  for (int off = 128; off > 0; off >>= 1) { if (t < off) red[t] += red[t+off]; __syncthreads(); }
  if (t == 0) dv[r] = 1.f / sqrtf(red[0] + 2.f);
}

// column pre-gather (level 1): AP[kk][c] = A[kk][perm[c]]
__global__ void k_gathercols(const float* __restrict__ A, int n, const int* __restrict__ perm,
                             int knext, float* __restrict__ AP) {
  int idx = blockIdx.x * 256 + threadIdx.x;
  int total = n * knext;
  if (idx >= total) return;
  int kk = idx / knext, c = idx - kk * knext;
  AP[idx] = A[(size_t)kk * n + perm[c]];
}

// level-1 augment+pool with fused rowsum/dinv
__global__ void k_augpool2_f(const float* __restrict__ A, const float* __restrict__ AP,
                             int n, const int* __restrict__ perm, int knext,
                             float* __restrict__ out, float* __restrict__ dv) {
  __shared__ float rowb[832];
  __shared__ float red[256];
  int r = blockIdx.x, t = threadIdx.x;
  int pr = perm[r];
  for (int i = t; i < n; i += 256) rowb[i] = A[(size_t)pr*n + i];
  __syncthreads();
  float local = 0.f;
  for (int c = t; c < knext; c += 256) {
    float dot = 0.f;
#pragma unroll 8
    for (int kk = 0; kk < n; kk++) dot += rowb[kk] * AP[(size_t)kk*knext + c];
    float val = (c == r) ? 0.f : (dot + 2.f * AP[(size_t)pr*knext + c]);
    out[(size_t)r*knext + c] = val;
    local += val;
  }
  red[t] = local; __syncthreads();
  for (int off = 128; off > 0; off >>= 1) { if (t < off) red[t] += red[t+off]; __syncthreads(); }
  if (t == 0) dv[r] = 1.f / sqrtf(red[0] + 2.f);
}

// small-level augment+pool (n <= 256): 8 threads per output column, fused rowsum/dinv
__global__ void k_augpool_small(const float* __restrict__ A, int n, const int* __restrict__ perm,
                                int knext, float* __restrict__ out, float* __restrict__ dv) {
  __shared__ float rowb[256];
  __shared__ float rsum;
  int r = blockIdx.x, t = threadIdx.x; // 256 threads
  int pr = perm[r];
  if (t < n) rowb[t] = A[(size_t)pr*n + t];
  if (t == 0) rsum = 0.f;
  __syncthreads();
  int g = t >> 3, lane = t & 7;
  for (int c = g; c < knext; c += 32) {
    int pc = perm[c];
    float part = 0.f;
    for (int kk = lane; kk < n; kk += 8) part += rowb[kk] * A[(size_t)kk*n + pc];
    part += __shfl_down(part, 4, 8);
    part += __shfl_down(part, 2, 8);
    part += __shfl_down(part, 1, 8);
    if (lane == 0) {
      float val = (c == r) ? 0.f : (part + 2.f * rowb[pc]);
      out[(size_t)r*knext + c] = val;
      atomicAdd(&rsum, val);
    }
  }
  __syncthreads();
  if (t == 0) dv[r] = 1.f / sqrtf(rsum + 2.f);
}

// dense GCN apply (branch-free streaming); optional score epilogue
__global__ void k_dense_gcn(const float* __restrict__ A, int n, const float* __restrict__ ts,
                            const float* __restrict__ dinv, float fill, const float* __restrict__ bias,
                            int relu, float* __restrict__ out,
                            const float* __restrict__ pw, const float* __restrict__ pwn1,
                            float* __restrict__ scoreo, unsigned long long* __restrict__ keyso,
                            int* __restrict__ ranko) {
  __shared__ float r2[2];
  int i = blockIdx.x, t = threadIdx.x;
  const float* Ar = A + (size_t)i * n;
  float acc = 0.f;
  int kk = 0;
  int n4 = n & ~3;
#pragma unroll 2
  for (; kk < n4; kk += 4) {
    float a0 = Ar[kk+0], a1 = Ar[kk+1], a2 = Ar[kk+2], a3 = Ar[kk+3];
    float t0 = ts[(size_t)(kk+0)*H + t];
    float t1 = ts[(size_t)(kk+1)*H + t];
    float t2 = ts[(size_t)(kk+2)*H + t];
    float t3 = ts[(size_t)(kk+3)*H + t];
    acc += a0*t0; acc += a1*t1; acc += a2*t2; acc += a3*t3;
  }
  for (; kk < n; kk++) acc += Ar[kk] * ts[(size_t)kk*H + t];
  float v = dinv[i] * (acc + fill * ts[(size_t)i*H + t]) + bias[t];
  if (relu) v = fmaxf(v, 0.f);
  out[(size_t)i*H + t] = v;
  if (pw) score_epilogue(v, i, t, pw, pwn1, scoreo, keyso, ranko, r2);
}

// up-path fused: (residual + inverse-perm scatter of xcur) @ W * dinv
__global__ void k_upproj(const float* __restrict__ xs, const int* __restrict__ inv,
                         const float* __restrict__ xcur, int kk,
                         const float* __restrict__ W, const float* __restrict__ dinv,
                         float* __restrict__ tsb) {
  __shared__ float hs[128];
  int i = blockIdx.x, t = threadIdx.x;
  int r = inv[i];
  float v = xs[(size_t)i*H + t];
  if (r < kk) v += xcur[(size_t)r*H + t];
  hs[t] = v;
  __syncthreads();
  float acc = 0.f;
  for (int k2 = 0; k2 < H; k2++) acc += hs[k2] * W[k2*H + t];
  tsb[(size_t)i*H + t] = acc * dinv[i];
}

// ts2[row,0:4] = dinv1_row * (cat([h1, relu(hbuf)]) @ Wout)[row,:]
__global__ void k_outproj_r(const float* __restrict__ h1, const float* __restrict__ hbuf,
                            const float* __restrict__ Wout, const float* __restrict__ dinv1,
                            float* __restrict__ ts2) {
  int row = blockIdx.x, t = threadIdx.x; // 64 threads
  float p0 = 0.f, p1 = 0.f, p2 = 0.f, p3 = 0.f;
#pragma unroll
  for (int half = 0; half < 2; half++) {
    float a = h1[(size_t)row*H + half*64 + t];
    const float* w = Wout + (half*64 + t)*4;
    p0 += a*w[0]; p1 += a*w[1]; p2 += a*w[2]; p3 += a*w[3];
    float b = fmaxf(hbuf[(size_t)row*H + half*64 + t], 0.f);
    const float* w2 = Wout + (128 + half*64 + t)*4;
    p0 += b*w2[0]; p1 += b*w2[1]; p2 += b*w2[2]; p3 += b*w2[3];
  }
  for (int off = 32; off > 0; off >>= 1) {
    p0 += __shfl_down(p0, off); p1 += __shfl_down(p1, off);
    p2 += __shfl_down(p2, off); p3 += __shfl_down(p3, off);
  }
  if (t == 0) {
    float d = dinv1[row];
    ts2[row*4+0] = d*p0; ts2[row*4+1] = d*p1; ts2[row*4+2] = d*p2; ts2[row*4+3] = d*p3;
  }
}

__global__ void k_gcn_out(const float* __restrict__ ts2, const int* __restrict__ rp,
                          const int* __restrict__ cols, const float* __restrict__ dinv1,
                          const float* __restrict__ bout, float* __restrict__ Fcur,
                          float* __restrict__ dout, int tstep) {
  int i = blockIdx.x, t = threadIdx.x; // 64 threads
  int f = t & 3;
  float acc = 0.f;
  int beg = rp[i], end = rp[i+1];
  for (int e = beg + (t >> 2); e < end; e += 16) acc += ts2[cols[e]*4 + f];
  for (int off = 32; off >= 4; off >>= 1) acc += __shfl_down(acc, off);
  if (t < 4) {
    float v = dinv1[i] * (acc + ts2[i*4 + f]) + bout[f];
    Fcur[i*4 + f] = v;
    dout[i*(NT*NF) + tstep*NF + f] = v;
  }
}

extern "C" void kernel_launch(void* const* d_in, const int* in_sizes, int n_in,
                              void* d_out, int out_size, void* d_ws, size_t ws_size,
                              hipStream_t stream) {
  const float* F0        = (const float*)d_in[0];
  const float* mesh_node = (const float*)d_in[1];
  const float* mesh_edge = (const float*)d_in[2];
  const float* Wm        = (const float*)d_in[3];
  const float* bm        = (const float*)d_in[4];
  const float* Wd0       = (const float*)d_in[5];
  const float* bd0       = (const float*)d_in[6];
  const float* Wd        = (const float*)d_in[7];
  const float* bd        = (const float*)d_in[8];
  const float* pool_w    = (const float*)d_in[9];
  const float* Wu        = (const float*)d_in[10];
  const float* bu        = (const float*)d_in[11];
  const float* Wout      = (const float*)d_in[12];
  const float* bout      = (const float*)d_in[13];
  const int*   ei        = (const int*)d_in[14];
  float* out = (float*)d_out;

  char* p = (char*)d_ws;
  auto carve = [&](size_t bytes) -> char* {
    char* r = p;
    p += (bytes + 255) & ~(size_t)255;
    return r;
  };
  int*   cnt    = (int*)carve((size_t)NN*4);
  int*   rp     = (int*)carve((size_t)(NN+1)*4);
  int*   cursor = (int*)carve((size_t)NN*4);
  int*   cols   = (int*)carve((size_t)EE*4);
  int*   permb  = (int*)carve((size_t)5*832*4);
  float* svb    = (float*)carve((size_t)5*832*4);
  float* dinv2  = (float*)carve((size_t)NN*4);
  float* dinv1  = (float*)carve((size_t)NN*4);
  float* pwn    = (float*)carve(8*4);
  float* S      = (float*)carve((size_t)NN*MEDGE*4);
  int*   invb   = (int*)carve((size_t)5*NN*4);
  float* P      = (float*)carve((size_t)NN*H*4);
  float* Q      = (float*)carve((size_t)NN*H*4);
  float* h1     = (float*)carve((size_t)NN*H*4);
  float* hbuf   = (float*)carve((size_t)NN*H*4);
  float* tsb    = (float*)carve((size_t)NN*H*4);
  float* tmp    = (float*)carve((size_t)NN*H*4);   // AP scratch
  float* x0     = (float*)carve((size_t)NN*H*4);
  float* x1     = (float*)carve((size_t)820*H*4);
  float* x2     = (float*)carve((size_t)164*H*4);
  float* x3     = (float*)carve((size_t)33*H*4);
  float* x4     = (float*)carve((size_t)7*H*4);
  float* xp     = (float*)carve((size_t)820*H*4);
  float* xcur   = (float*)carve((size_t)820*H*4);
  float* score  = (float*)carve((size_t)NN*4);
  unsigned long long* keysb = (unsigned long long*)carve((size_t)NN*8);
  int*   rankb  = (int*)carve((size_t)NN*4);
  float* A820   = (float*)carve((size_t)820*820*4);
  float* A164   = (float*)carve((size_t)164*164*4);
  float* A33    = (float*)carve((size_t)33*33*4);
  float* A7     = (float*)carve((size_t)7*7*4);
  float* A2b    = (float*)carve((size_t)2*2*4);
  float* dv820  = (float*)carve(820*4);
  float* dv164  = (float*)carve(164*4);
  float* dv33   = (float*)carve(33*4);
  float* dv7    = (float*)carve(7*4);
  float* dv2    = (float*)carve(2*4);
  float* ts2    = (float*)carve((size_t)NN*NF*4);
  float* Fcur   = (float*)carve((size_t)NN*NF*4);

  float* AP = tmp;

  int* perml[5]; float* svl[5]; int* invl[5];
  for (int l = 0; l < 5; l++) {
    perml[l] = permb + l*832; svl[l] = svb + l*832; invl[l] = invb + l*NN;
  }

  // ---- setup (once per launch) ----
  hipMemsetAsync(cnt, 0, (size_t)NN*4, stream);
  hipMemsetAsync(S, 0, (size_t)NN*MEDGE*4, stream);
  hipMemsetAsync(hbuf, 0, (size_t)NN*H*4, stream);
  k_count<<<EE/256, 256, 0, stream>>>(ei + EE, cnt);
  k_scan<<<1, 1024, 0, stream>>>(cnt, rp);
  hipMemcpyAsync(cursor, rp, (size_t)NN*4, hipMemcpyDeviceToDevice, stream);
  k_fill<<<EE/256, 256, 0, stream>>>(ei, cursor, cols);
  k_dinv0<<<NN/256, 256, 0, stream>>>(cnt, dinv2, dinv1);
  k_pwnorm<<<5, 64, 0, stream>>>(pool_w, pwn);
  k_segS<<<EE/256, 256, 0, stream>>>(ei + EE, mesh_edge, S);
  hipMemcpyAsync(Fcur, F0, (size_t)NN*NF*4, hipMemcpyDeviceToDevice, stream);

  for (int step = 0; step < NT; step++) {
    // edge MLP -> h1 -> Wd0 proj; x0 with L0 score epilogue
    k_mm_cat<<<NN, 128, 0, stream>>>(Fcur, mesh_node, hbuf, Wm, P, Q);
    k_spmm_h1_mm<<<NN, 128, 0, stream>>>(Q, rp, cols, P, bm, S, Wm + 280*H, cnt,
                                         Wd0, dinv2, h1, tsb);
    k_spmm_fused<<<NN, 128, 0, stream>>>(tsb, rp, cols, dinv2, 2.f, bd0, 1, x0,
                                         pool_w, pwn, score, keysb, rankb);

    // L0: pool 4096->820 (score from epilogue above)
    k_count_rank<<<dim3(16, 16), 256, 0, stream>>>(keysb, NN, rankb);
    k_select<<<16, 256, 0, stream>>>(score, rankb, NN, 820, perml[0], svl[0], invl[0]);
    k_a820_f<<<820, 256, 0, stream>>>(rp, cols, perml[0], A820, dv820);
    k_mm_pool<<<820, 128, 0, stream>>>(x0, perml[0], svl[0], Wd, tsb, dv820);
    k_dense_gcn<<<820, 128, 0, stream>>>(A820, 820, tsb, dv820, 2.f, bd, 1, x1,
                                         pool_w + H, pwn + 1, score, keysb, rankb);

    // L1: pool 820->164
    k_count_rank<<<dim3(4, 4), 256, 0, stream>>>(keysb, 820, rankb);
    k_select<<<4, 256, 0, stream>>>(score, rankb, 820, 164, perml[1], svl[1], invl[1]);
    k_gathercols<<<(820*164 + 255)/256, 256, 0, stream>>>(A820, 820, perml[1], 164, AP);
    k_augpool2_f<<<164, 256, 0, stream>>>(A820, AP, 820, perml[1], 164, A164, dv164);
    k_mm_pool<<<164, 128, 0, stream>>>(x1, perml[1], svl[1], Wd + 1*H*H, tsb, dv164);
    k_dense_gcn<<<164, 128, 0, stream>>>(A164, 164, tsb, dv164, 2.f, bd + 1*H, 1, x2,
                                         pool_w + 2*H, pwn + 2, score, keysb, rankb);

    // L2: pool 164->33 (keys from L1's dense_gcn epilogue)
    k_pool_small<<<1, 256, 0, stream>>>(score, keysb, x2, 164, 33, perml[2], svl[2], invl[2], xp);
    k_augpool_small<<<33, 256, 0, stream>>>(A164, 164, perml[2], 33, A33, dv33);
    k_mm_rb<<<33, 128, 0, stream>>>(xp, Wd + 2*H*H, tsb, dv33);
    k_dense_gcn<<<33, 128, 0, stream>>>(A33, 33, tsb, dv33, 2.f, bd + 2*H, 1, x3,
                                        pool_w + 3*H, pwn + 3, score, keysb, rankb);

    // L3: pool 33->7
    k_pool_small<<<1, 256, 0, stream>>>(score, keysb, x3, 33, 7, perml[3], svl[3], invl[3], xp);
    k_augpool_small<<<7, 256, 0, stream>>>(A33, 33, perml[3], 7, A7, dv7);
    k_mm_rb<<<7, 128, 0, stream>>>(xp, Wd + 3*H*H, tsb, dv7);
    k_dense_gcn<<<7, 128, 0, stream>>>(A7, 7, tsb, dv7, 2.f, bd + 3*H, 1, x4,
                                       pool_w + 4*H, pwn + 4, score, keysb, rankb);

    // L4: pool 7->2
    k_pool_small<<<1, 256, 0, stream>>>(score, keysb, x4, 7, 2, perml[4], svl[4], invl[4], xp);
    k_augpool_small<<<2, 256, 0, stream>>>(A7, 7, perml[4], 2, A2b, dv2);
    k_mm_rb<<<2, 128, 0, stream>>>(xp, Wd + 4*H*H, tsb, dv2);
    k_dense_gcn<<<2, 128, 0, stream>>>(A2b, 2, tsb, dv2, 2.f, bd + 4*H, 1, xcur,
                                       nullptr, nullptr, nullptr, nullptr, nullptr);

    // up path: j=4,3,2,1,0  (i = 0..4)
    k_upproj<<<7, 128, 0, stream>>>(x4, invl[4], xcur, 2, Wu, dv7, tsb);
    k_dense_gcn<<<7, 128, 0, stream>>>(A7, 7, tsb, dv7, 2.f, bu, 1, xcur,
                                       nullptr, nullptr, nullptr, nullptr, nullptr);
    k_upproj<<<33, 128, 0, stream>>>(x3, invl[3], xcur, 7, Wu + 1*H*H, dv33, tsb);
    k_dense_gcn<<<33, 128, 0, stream>>>(A33, 33, tsb, dv33, 2.f, bu + 1*H, 1, xcur,
                                        nullptr, nullptr, nullptr, nullptr, nullptr);
    k_upproj<<<164, 128, 0, stream>>>(x2, invl[2], xcur, 33, Wu + 2*H*H, dv164, tsb);
    k_dense_gcn<<<164, 128, 0, stream>>>(A164, 164, tsb, dv164, 2.f, bu + 2*H, 1, xcur,
                                         nullptr, nullptr, nullptr, nullptr, nullptr);
    k_upproj<<<820, 128, 0, stream>>>(x1, invl[1], xcur, 164, Wu + 3*H*H, dv820, tsb);
    k_dense_gcn<<<820, 128, 0, stream>>>(A820, 820, tsb, dv820, 2.f, bu + 3*H, 1, xcur,
                                         nullptr, nullptr, nullptr, nullptr, nullptr);
    k_upproj<<<NN, 128, 0, stream>>>(x0, invl[0], xcur, 820, Wu + 4*H*H, dinv2, tsb);
    k_spmm_fused<<<NN, 128, 0, stream>>>(tsb, rp, cols, dinv2, 2.f, bu + 4*H, 0, hbuf,
                                         nullptr, nullptr, nullptr, nullptr, nullptr);

    // output GCN (fill=1)
    k_outproj_r<<<NN, 64, 0, stream>>>(h1, hbuf, Wout, dinv1, ts2);
    k_gcn_out<<<NN, 64, 0, stream>>>(ts2, rp, cols, dinv1, bout, Fcur, out, step);
  }
}